// Round 9
// baseline (22.856 us; speedup 1.0000x reference)
//
#include <hip/hip_runtime.h>

#define THREADS 256
#define NTILE 8

#define S_CONST    12102203.161561485f  // 2^23 * log2(e)
#define BIAS_CONST 1064872549.0f        // 127*2^23 - 480667 (mean-centered Schraudolph)

// Pin a (provably wave-uniform) float into an SGPR.
static __device__ __forceinline__ float uni(float x) {
    return __int_as_float(__builtin_amdgcn_readfirstlane(__float_as_int(x)));
}

// iso (s0==s1): t = A + D*r2 + B*x0 + C*x1 ; exp via Schraudolph bitcast.
// B,C,D live in SGPRs: each v_fma_f32 reads exactly 1 SGPR (legal).
static __device__ __forceinline__ void body_iso(
    float x0, float x1, float mk,
    const float* cA, const float* cB, const float* cC, const float* cD,
    float* acc)
{
    const float r2 = __builtin_fmaf(x1, x1, x0 * x0);
#pragma unroll
    for (int i = 0; i < NTILE; ++i) {
        float t = __builtin_fmaf(cD[i], r2, cA[i]);
        t = __builtin_fmaf(cB[i], x0, t);
        t = __builtin_fmaf(cC[i], x1, t);
        acc[i] = __builtin_fmaf(__int_as_float((int)t), mk, acc[i]);
    }
}

// generic: t = A + B*x0 + C*x1 + D*x0^2 + E*x1^2
static __device__ __forceinline__ void body_gen(
    float x0, float x1, float mk,
    const float* cA, const float* cB, const float* cC, const float* cD,
    const float* cE, float* acc)
{
    const float sq0 = x0 * x0, sq1 = x1 * x1;
#pragma unroll
    for (int i = 0; i < NTILE; ++i) {
        float t = __builtin_fmaf(cB[i], x0, cA[i]);
        t = __builtin_fmaf(cC[i], x1, t);
        t = __builtin_fmaf(cD[i], sq0, t);
        t = __builtin_fmaf(cE[i], sq1, t);
        acc[i] = __builtin_fmaf(__int_as_float((int)t), mk, acc[i]);
    }
}

// Register-double-buffered loop over quad range [qlo, qhi).
template <bool ISO>
static __device__ __forceinline__ void main_loop(
    const float4* B4, const float4* M4, int qlo, int qhi, int tid,
    const float* cA, const float* cB, const float* cC, const float* cD,
    const float* cE, float* acc)
{
    int q = qlo + tid;
    if (q >= qhi) return;
    float4 pa = B4[2 * q], pb = B4[2 * q + 1], pm = M4[q];
    while (true) {
        const int qn = q + THREADS;
        const bool vn = qn < qhi;
        const int qc = vn ? qn : q;  // clamp: loads always valid, unused on exit
        float4 na = B4[2 * qc], nb = B4[2 * qc + 1], nm = M4[qc];

        if (ISO) {
            body_iso(pa.x, pa.y, pm.x, cA, cB, cC, cD, acc);
            body_iso(pa.z, pa.w, pm.y, cA, cB, cC, cD, acc);
            body_iso(pb.x, pb.y, pm.z, cA, cB, cC, cD, acc);
            body_iso(pb.z, pb.w, pm.w, cA, cB, cC, cD, acc);
        } else {
            body_gen(pa.x, pa.y, pm.x, cA, cB, cC, cD, cE, acc);
            body_gen(pa.z, pa.w, pm.y, cA, cB, cC, cD, cE, acc);
            body_gen(pb.x, pb.y, pm.z, cA, cB, cC, cD, cE, acc);
            body_gen(pb.z, pb.w, pm.w, cA, cB, cC, cD, cE, acc);
        }

        if (!vn) break;
        q = qn; pa = na; pb = nb; pm = nm;
    }
}

// Grid = T * B * 2: P split in two halves -> 2048 blocks = 8 blocks/CU =
// 8 waves/SIMD supplied at the proven 256-thread shape. Each out[b,n] gets
// exactly TWO atomicAdd contributions (fp add commutative => 2-way
// order-invariant, bit-exact deterministic). d_out zeroed via memsetAsync.
__global__ __launch_bounds__(THREADS, 8) void slayer_exp_kernel(
    const float* __restrict__ batch,      // [B,P,2]
    const float* __restrict__ not_dummy,  // [B,P]
    const float* __restrict__ centers,    // [N,2]
    const float* __restrict__ sharpness,  // [N,2]
    float* __restrict__ out,              // [B,N]
    int B, int P, int N, int T)           // T = n-tiles per b
{
    // XCD-locality swizzle: the 2T blocks sharing one b land on the SAME XCD.
    const int id = blockIdx.x;
    int b, j, half;
    if ((B & 7) == 0) {
        const int xcd = id & 7;
        const int r = id >> 3;
        j = r % T;
        half = (r / T) & 1;
        b = (r / (2 * T)) * 8 + xcd;
    } else {
        b = id / (2 * T);
        const int rem = id % (2 * T);
        half = rem / T;
        j = rem % T;
    }
    const int n0  = j * NTILE;
    const int tid = threadIdx.x;

    // Per-center constants. A stays in VGPR (fma already uses its 1 SGPR slot);
    // B,C,D,E pinned to SGPRs via readfirstlane (block-uniform by construction).
    float cA[NTILE], cB[NTILE], cC[NTILE], cD[NTILE], cE[NTILE];
    bool iso = true;
#pragma unroll
    for (int i = 0; i < NTILE; ++i) {
        int n = n0 + i; if (n >= N) n = N - 1;
        const float c0 = centers[2 * n], c1 = centers[2 * n + 1];
        const float s0 = sharpness[2 * n], s1 = sharpness[2 * n + 1];
        cA[i] = BIAS_CONST - S_CONST * (s0 * c0 * c0 + s1 * c1 * c1);
        cB[i] = uni(S_CONST * 2.0f * s0 * c0);
        cC[i] = uni(S_CONST * 2.0f * s1 * c1);
        cD[i] = uni(-S_CONST * s0);
        cE[i] = uni(-S_CONST * s1);
        iso = iso && (s0 == s1);
    }

    float acc[NTILE];
#pragma unroll
    for (int i = 0; i < NTILE; ++i) acc[i] = 0.0f;

    const float4* B4 = (const float4*)(batch + (size_t)b * P * 2);
    const float4* M4 = (const float4*)(not_dummy + (size_t)b * P);
    const int quadsT = P >> 2;
    const int qmid   = quadsT >> 1;
    const int qlo    = half ? qmid : 0;
    const int qhi    = half ? quadsT : qmid;

    if (iso) main_loop<true>(B4, M4, qlo, qhi, tid, cA, cB, cC, cD, cE, acc);
    else     main_loop<false>(B4, M4, qlo, qhi, tid, cA, cB, cC, cD, cE, acc);

    // Tail: P % 4 leftover points (not hit for P=8192); half-1, thread 0 only.
    if ((P & 3) && half == 1 && tid == 0) {
        const float* bb = batch + (size_t)b * P * 2;
        const float* mm = not_dummy + (size_t)b * P;
        for (int p = (quadsT << 2); p < P; ++p)
            body_gen(bb[2 * p], bb[2 * p + 1], mm[p], cA, cB, cC, cD, cE, acc);
    }

    // Wave-level butterfly reduction (64 lanes), then cross-wave via LDS.
#pragma unroll
    for (int i = 0; i < NTILE; ++i) {
        float v = acc[i];
#pragma unroll
        for (int off = 32; off >= 1; off >>= 1)
            v += __shfl_xor(v, off, 64);
        acc[i] = v;
    }

    __shared__ float red[THREADS / 64][NTILE];
    const int wave = tid >> 6;
    const int lane = tid & 63;
    if (lane == 0) {
#pragma unroll
        for (int i = 0; i < NTILE; ++i) red[wave][i] = acc[i];
    }
    __syncthreads();

    if (tid < NTILE && (n0 + tid) < N) {
        float v = 0.0f;
#pragma unroll
        for (int w = 0; w < THREADS / 64; ++w) v += red[w][tid];
        atomicAdd(&out[(size_t)b * N + n0 + tid], v);
    }
}

extern "C" void kernel_launch(void* const* d_in, const int* in_sizes, int n_in,
                              void* d_out, int out_size, void* d_ws, size_t ws_size,
                              hipStream_t stream) {
    const float* batch     = (const float*)d_in[0];
    const float* not_dummy = (const float*)d_in[1];
    const float* centers   = (const float*)d_in[2];
    const float* sharp     = (const float*)d_in[3];
    float* out = (float*)d_out;

    const int N  = in_sizes[2] / 2;       // centers: [N,2]
    const int BP = in_sizes[1];           // not_dummy: [B,P]
    const int B  = out_size / N;          // out: [B,N]
    const int P  = BP / B;
    const int T  = (N + NTILE - 1) / NTILE;

    hipMemsetAsync(out, 0, (size_t)out_size * sizeof(float), stream);

    dim3 grid(T * B * 2);
    slayer_exp_kernel<<<grid, THREADS, 0, stream>>>(batch, not_dummy, centers, sharp,
                                                    out, B, P, N, T);
}

// Round 10
// 15.638 us; speedup vs baseline: 1.4616x; 1.4616x over previous
//
#include <hip/hip_runtime.h>

#define THREADS 256
#define NTILE 8

#define S_CONST    12102203.161561485f  // 2^23 * log2(e)
#define BIAS_CONST 1064872549.0f        // 127*2^23 - 480667 (mean-centered Schraudolph)

// Pin a (provably wave-uniform) float into an SGPR.
static __device__ __forceinline__ float uni(float x) {
    return __int_as_float(__builtin_amdgcn_readfirstlane(__float_as_int(x)));
}

// iso (s0==s1): t = A + D*r2 + B*x0 + C*x1 ; exp via Schraudolph bitcast.
// B,C,D in SGPRs, A in VGPR: each v_fma_f32 reads exactly 1 SGPR (legal),
// zero splat/mov overhead (this was the hidden ~20% cost of the pk body).
static __device__ __forceinline__ void body_iso(
    float x0, float x1, float mk,
    const float* cA, const float* cB, const float* cC, const float* cD,
    float* acc)
{
    const float r2 = __builtin_fmaf(x1, x1, x0 * x0);
#pragma unroll
    for (int i = 0; i < NTILE; ++i) {
        float t = __builtin_fmaf(cD[i], r2, cA[i]);
        t = __builtin_fmaf(cB[i], x0, t);
        t = __builtin_fmaf(cC[i], x1, t);
        acc[i] = __builtin_fmaf(__int_as_float((int)t), mk, acc[i]);
    }
}

// generic: t = A + B*x0 + C*x1 + D*x0^2 + E*x1^2
static __device__ __forceinline__ void body_gen(
    float x0, float x1, float mk,
    const float* cA, const float* cB, const float* cC, const float* cD,
    const float* cE, float* acc)
{
    const float sq0 = x0 * x0, sq1 = x1 * x1;
#pragma unroll
    for (int i = 0; i < NTILE; ++i) {
        float t = __builtin_fmaf(cB[i], x0, cA[i]);
        t = __builtin_fmaf(cC[i], x1, t);
        t = __builtin_fmaf(cD[i], sq0, t);
        t = __builtin_fmaf(cE[i], sq1, t);
        acc[i] = __builtin_fmaf(__int_as_float((int)t), mk, acc[i]);
    }
}

// Register-double-buffered loop (clamped prefetch, no exec-mask dance).
template <bool ISO>
static __device__ __forceinline__ void main_loop(
    const float4* B4, const float4* M4, int quads, int tid,
    const float* cA, const float* cB, const float* cC, const float* cD,
    const float* cE, float* acc)
{
    int q = tid;
    if (q >= quads) return;
    float4 pa = B4[2 * q], pb = B4[2 * q + 1], pm = M4[q];
    while (true) {
        const int qn = q + THREADS;
        const bool vn = qn < quads;
        const int qc = vn ? qn : q;  // clamp: loads always valid, unused on exit
        float4 na = B4[2 * qc], nb = B4[2 * qc + 1], nm = M4[qc];

        if (ISO) {
            body_iso(pa.x, pa.y, pm.x, cA, cB, cC, cD, acc);
            body_iso(pa.z, pa.w, pm.y, cA, cB, cC, cD, acc);
            body_iso(pb.x, pb.y, pm.z, cA, cB, cC, cD, acc);
            body_iso(pb.z, pb.w, pm.w, cA, cB, cC, cD, acc);
        } else {
            body_gen(pa.x, pa.y, pm.x, cA, cB, cC, cD, cE, acc);
            body_gen(pa.z, pa.w, pm.y, cA, cB, cC, cD, cE, acc);
            body_gen(pb.x, pb.y, pm.z, cA, cB, cC, cD, cE, acc);
            body_gen(pb.z, pb.w, pm.w, cA, cB, cC, cD, cE, acc);
        }

        if (!vn) break;
        q = qn; pa = na; pb = nb; pm = nm;
    }
}

__global__ __launch_bounds__(THREADS, 4) void slayer_exp_kernel(
    const float* __restrict__ batch,      // [B,P,2]
    const float* __restrict__ not_dummy,  // [B,P]
    const float* __restrict__ centers,    // [N,2]
    const float* __restrict__ sharpness,  // [N,2]
    float* __restrict__ out,              // [B,N]
    int B, int P, int N, int T)           // T = n-tiles per b
{
    // XCD-locality swizzle: the T blocks sharing one b land on the SAME XCD.
    const int id = blockIdx.x;
    int b, j;
    if ((B & 7) == 0) {
        const int r = id >> 3;
        j = r % T;
        b = (r / T) * 8 + (id & 7);
    } else {
        b = id / T;
        j = id % T;
    }
    const int n0  = j * NTILE;
    const int tid = threadIdx.x;

    // Per-center constants. A stays in VGPR (fma's 1-SGPR slot goes to B/C/D/E,
    // which are pinned to SGPRs via readfirstlane — block-uniform by construction).
    float cA[NTILE], cB[NTILE], cC[NTILE], cD[NTILE], cE[NTILE];
    bool iso = true;
#pragma unroll
    for (int i = 0; i < NTILE; ++i) {
        int n = n0 + i; if (n >= N) n = N - 1;
        const float c0 = centers[2 * n], c1 = centers[2 * n + 1];
        const float s0 = sharpness[2 * n], s1 = sharpness[2 * n + 1];
        cA[i] = BIAS_CONST - S_CONST * (s0 * c0 * c0 + s1 * c1 * c1);
        cB[i] = uni(S_CONST * 2.0f * s0 * c0);
        cC[i] = uni(S_CONST * 2.0f * s1 * c1);
        cD[i] = uni(-S_CONST * s0);
        cE[i] = uni(-S_CONST * s1);
        iso = iso && (s0 == s1);
    }

    float acc[NTILE];
#pragma unroll
    for (int i = 0; i < NTILE; ++i) acc[i] = 0.0f;

    const float4* B4 = (const float4*)(batch + (size_t)b * P * 2);
    const float4* M4 = (const float4*)(not_dummy + (size_t)b * P);
    const int quads = P >> 2;

    if (iso) main_loop<true>(B4, M4, quads, tid, cA, cB, cC, cD, cE, acc);
    else     main_loop<false>(B4, M4, quads, tid, cA, cB, cC, cD, cE, acc);

    // Tail: P % 4 leftover points (not hit for P=8192), thread 0, scalar.
    if ((P & 3) && tid == 0) {
        const float* bb = batch + (size_t)b * P * 2;
        const float* mm = not_dummy + (size_t)b * P;
        for (int p = (quads << 2); p < P; ++p)
            body_gen(bb[2 * p], bb[2 * p + 1], mm[p], cA, cB, cC, cD, cE, acc);
    }

    // Wave-level butterfly reduction (64 lanes), then cross-wave via LDS.
#pragma unroll
    for (int i = 0; i < NTILE; ++i) {
        float v = acc[i];
#pragma unroll
        for (int off = 32; off >= 1; off >>= 1)
            v += __shfl_xor(v, off, 64);
        acc[i] = v;
    }

    __shared__ float red[THREADS / 64][NTILE];
    const int wave = tid >> 6;
    const int lane = tid & 63;
    if (lane == 0) {
#pragma unroll
        for (int i = 0; i < NTILE; ++i) red[wave][i] = acc[i];
    }
    __syncthreads();

    if (tid < NTILE && (n0 + tid) < N) {
        float v = 0.0f;
#pragma unroll
        for (int w = 0; w < THREADS / 64; ++w) v += red[w][tid];
        out[(size_t)b * N + n0 + tid] = v;
    }
}

extern "C" void kernel_launch(void* const* d_in, const int* in_sizes, int n_in,
                              void* d_out, int out_size, void* d_ws, size_t ws_size,
                              hipStream_t stream) {
    const float* batch     = (const float*)d_in[0];
    const float* not_dummy = (const float*)d_in[1];
    const float* centers   = (const float*)d_in[2];
    const float* sharp     = (const float*)d_in[3];
    float* out = (float*)d_out;

    const int N  = in_sizes[2] / 2;       // centers: [N,2]
    const int BP = in_sizes[1];           // not_dummy: [B,P]
    const int B  = out_size / N;          // out: [B,N]
    const int P  = BP / B;
    const int T  = (N + NTILE - 1) / NTILE;

    dim3 grid(T * B);
    slayer_exp_kernel<<<grid, THREADS, 0, stream>>>(batch, not_dummy, centers, sharp,
                                                    out, B, P, N, T);
}